// Round 7
// baseline (5029.268 us; speedup 1.0000x reference)
//
#include <hip/hip_runtime.h>
#include <hip/hip_bf16.h>
#include <stdint.h>

typedef __hip_bfloat16 bf16_t;
typedef __attribute__((ext_vector_type(4))) float f32x4;
typedef __attribute__((ext_vector_type(8))) short s16x8;

#define UNITS 768
#define NCOLS 3072        // 4*UNITS (gates, reordered)
#define NPRED 96
#define MROWS 2048

__device__ __forceinline__ float sigf(float x) {
    return __builtin_amdgcn_rcpf(1.f + __expf(-x));
}
__device__ __forceinline__ float tanh_fast(float x) {
    return 1.f - 2.f * __builtin_amdgcn_rcpf(1.f + __expf(2.f * x));
}

// ---------------- prep kernels (once per launch) ---------------

__global__ void prep_zero(unsigned int* c) {
    if (threadIdx.x < 64) c[threadIdx.x] = 0u;
}

// B0T[c][k] = W_ih[g*768+u][k], c-reordered (linear), K=96
__global__ void prep_b0(const float* __restrict__ W_ih, bf16_t* __restrict__ B0T) {
    int idx = blockIdx.x * 256 + threadIdx.x;
    if (idx >= NCOLS * 96) return;
    int c = idx / 96, k = idx % 96;
    int u = ((c >> 6) << 4) + (c & 15);
    int g = (c >> 4) & 3;
    B0T[idx] = (bf16_t)W_ih[(g * UNITS + u) * 96 + k];
}

// x0 in A-fragment layout: elem((mf*3+kf)*512 + l*8 + j) = x[mf*16+(l&15)][kf*32+(l>>4)*8+j]
__global__ void prep_x0(const float* __restrict__ inputs, bf16_t* __restrict__ x0) {
    int idx = blockIdx.x * 256 + threadIdx.x; // 2048*96 = 196608 exactly
    int j = idx & 7;
    int l = (idx >> 3) & 63;
    int fg = idx >> 9;          // mf*3 + kf
    int kf = fg % 3;
    int mf = fg / 3;
    int m = mf * 16 + (l & 15);
    int k = kf * 32 + (l >> 4) * 8 + j;
    x0[idx] = (bf16_t)inputs[(m * 24 + 23) * 96 + k];
}

__global__ void prep_bias(const float* __restrict__ b_ih, const float* __restrict__ b_hh,
                          const float* __restrict__ W_ih, const float* __restrict__ b_d,
                          float* __restrict__ b0_r, float* __restrict__ beff_r) {
    int c = blockIdx.x * 256 + threadIdx.x;
    if (c >= NCOLS) return;
    int u = ((c >> 6) << 4) + (c & 15);
    int g = (c >> 4) & 3;
    int r = g * UNITS + u;
    float v = b_ih[r] + b_hh[r];
    float acc = 0.f;
    for (int j = 0; j < 96; ++j) acc += W_ih[r * 96 + j] * b_d[j];
    b0_r[c] = v;
    beff_r[c] = v + acc;
}

// BeffT[c][k] = W_hh[r(c)][k] + sum_j W_ih[r(c)][j]*W_d[j][k]   (c<3072, LDS-tiled)
__global__ void prep_beff2(const float* __restrict__ W_hh, const float* __restrict__ W_ih,
                           const float* __restrict__ W_d, bf16_t* __restrict__ BeffT) {
    __shared__ float sWih[64][96];
    __shared__ float sWd[96][64];
    const int c0 = blockIdx.x * 64, k0 = blockIdx.y * 64;
    const int tid = threadIdx.x;
    for (int i = tid; i < 64 * 96; i += 256) {
        int cc = i / 96, j = i % 96;
        int c = c0 + cc;
        int u = ((c >> 6) << 4) + (c & 15);
        int g = (c >> 4) & 3;
        sWih[cc][j] = W_ih[(g * UNITS + u) * 96 + j];
    }
    for (int i = tid; i < 96 * 64; i += 256) {
        int j = i / 64, kk = i % 64;
        sWd[j][kk] = W_d[j * UNITS + k0 + kk];
    }
    __syncthreads();
    const int kk = tid & 63;
    const int cc0 = (tid >> 6) * 16;
    for (int cc = cc0; cc < cc0 + 16; ++cc) {
        float acc = 0.f;
#pragma unroll 12
        for (int j = 0; j < 96; ++j) acc += sWih[cc][j] * sWd[j][kk];
        int c = c0 + cc;
        int u = ((c >> 6) << 4) + (c & 15);
        int g = (c >> 4) & 3;
        int r = g * UNITS + u;
        BeffT[(size_t)c * UNITS + k0 + kk] = (bf16_t)(W_hh[(size_t)r * UNITS + k0 + kk] + acc);
    }
}

// rows 3072..3199 of BeffT: W_d rows then zero pad
__global__ void prep_wdt(const float* __restrict__ W_d, bf16_t* __restrict__ BeffT) {
    int idx = blockIdx.x * 256 + threadIdx.x; // 128*768
    int c = idx / UNITS, k = idx % UNITS;
    float v = (c < NPRED) ? W_d[c * UNITS + k] : 0.f;
    BeffT[(size_t)(NCOLS + c) * UNITS + k] = (bf16_t)v;
}

// swizzle linear [c][K] -> B-fragment order
__global__ void prep_swz(const bf16_t* __restrict__ src, bf16_t* __restrict__ dst,
                         int Knk, int K, int total) {
    int idx = blockIdx.x * 256 + threadIdx.x;
    if (idx >= total) return;
    int j = idx & 7;
    int l = (idx >> 3) & 63;
    int fg = idx >> 9;
    int f = fg & 3;
    int rest = fg >> 2;
    int kf = rest % Knk;
    int nw = rest / Knk;
    int c = (nw >> 1) * 128 + (nw & 1) * 64 + f * 16 + (l & 15);
    int k = kf * 32 + (l >> 4) * 8 + j;
    dst[idx] = src[(size_t)c * K + k];
}

// ---------------- persistent kernel: one dispatch, all 64 steps ---------------
// 256 blocks x 256 threads, exactly 1 block/CU (cooperative launch guarantees
// residency). Tiles: 200 active blocks, tile id in [0,200): mt=id&7 (M=256 rows),
// nt=id>>3 (N=128 cols; nt==24 is the pred tile). c-state in registers.
// Inter-step sync: global arrive counter + __threadfence pair (agent release:
// buffer_wbl2 flushes h to L3; acquire: buffer_inv drops stale L1/L2). Weights
// are read-only -> stay L3-resident; no grid.sync -> no HBM refetch (R1 bug).
__global__ __launch_bounds__(256, 1)
void persist_kernel(const bf16_t* __restrict__ x0s,
                    const bf16_t* __restrict__ B0s,
                    const bf16_t* __restrict__ Bs,
                    const float* __restrict__ b0r,
                    const float* __restrict__ beffr,
                    const float* __restrict__ b_d,
                    bf16_t* __restrict__ h0,
                    bf16_t* __restrict__ h1,
                    float* __restrict__ out,
                    unsigned int* __restrict__ ctrs)
{
    const int tid = threadIdx.x;
    const int wave = tid >> 6;
    const int lane = tid & 63;
    const int l15 = lane & 15, l4 = lane >> 4;

    __shared__ int s_id;

    // ---- phase 0: placement-aware, placement-independent-correct assignment ----
    if (tid == 0) {
        unsigned int x;
        asm volatile("s_getreg_b32 %0, hwreg(20, 0, 32)" : "=s"(x));  // HW_REG_XCC_ID
        x &= 7u;
        unsigned int r = atomicAdd(&ctrs[x], 1u);     // rank within (claimed) XCD
        __threadfence();                               // rk-add visible before greg-add
        unsigned int gq = atomicAdd(&ctrs[8], 1u);     // global registration rank
        while (__hip_atomic_load(&ctrs[8], __ATOMIC_RELAXED, __HIP_MEMORY_SCOPE_AGENT) < 256u)
            __builtin_amdgcn_s_sleep(2);
        __threadfence();
        unsigned int mn = 0xffffffffu;
        for (int y = 0; y < 8; ++y) {
            unsigned int v = __hip_atomic_load(&ctrs[y], __ATOMIC_RELAXED, __HIP_MEMORY_SCOPE_AGENT);
            mn = (v < mn) ? v : mn;
        }
        int id;
        if (mn >= 25u) id = (r < 25u) ? (int)(x * 25u + r) : -1;   // XCD-local tiles
        else           id = (gq < 200u) ? (int)gq : -1;            // robust fallback
        s_id = id;
    }
    __syncthreads();
    const int id = s_id;
    const bool active = (id >= 0);
    const int mt = active ? (id & 7) : 0;       // M-tile: rows [mt*256, mt*256+256)
    const int nt = active ? (id >> 3) : 0;      // N-tile: cols [nt*128, ...)
    const bool is_pred = active && (nt == 24);

    unsigned int* bar = &ctrs[9];
    bf16_t* hbuf[2] = {h0, h1};

    // ---- per-lane constants ----
    float bi0[8], biE[8];
    if (active) {
        if (!is_pred) {
#pragma unroll
            for (int f = 0; f < 8; ++f) {
                bi0[f] = b0r[nt * 128 + f * 16 + l15];
                biE[f] = beffr[nt * 128 + f * 16 + l15];
            }
        } else {
#pragma unroll
            for (int f = 0; f < 8; ++f) {
                int col = f * 16 + l15;
                biE[f] = (col < NPRED) ? b_d[col] : 0.f;
                bi0[f] = biE[f];
            }
        }
    }

    // c-state in registers: 32 values/lane = rows(4 frags x 4) x unit-groups(2)
    float cr[4][4][2];
#pragma unroll
    for (int i = 0; i < 4; ++i)
#pragma unroll
        for (int r = 0; r < 4; ++r) { cr[i][r][0] = 0.f; cr[i][r][1] = 0.f; }

    for (int n = 0; n <= 64; ++n) {
        const bool doit = active && (n == 0 ? !is_pred : (n == 64 ? is_pred : true));
        if (doit) {
            f32x4 acc[4][8];
#pragma unroll
            for (int i = 0; i < 4; ++i)
#pragma unroll
                for (int f = 0; f < 8; ++f) acc[i][f] = f32x4{0.f, 0.f, 0.f, 0.f};

            if (n == 0) {
                // K=96 (3 kf) from x0s/B0s, all register-resident
                s16x8 a3[3][4], b3[3][8];
#pragma unroll
                for (int p = 0; p < 3; ++p) {
#pragma unroll
                    for (int i = 0; i < 4; ++i)
                        a3[p][i] = *(const s16x8*)(x0s + ((size_t)((mt * 16 + wave * 4 + i) * 3 + p)) * 512 + lane * 8);
#pragma unroll
                    for (int f = 0; f < 8; ++f)
                        b3[p][f] = *(const s16x8*)(B0s + ((size_t)(((nt * 2 + (f >> 2)) * 3 + p) * 4 + (f & 3))) * 512 + lane * 8);
                }
#pragma unroll
                for (int p = 0; p < 3; ++p)
#pragma unroll
                    for (int i = 0; i < 4; ++i)
#pragma unroll
                        for (int f = 0; f < 8; ++f)
                            acc[i][f] = __builtin_amdgcn_mfma_f32_16x16x32_bf16(a3[p][i], b3[p][f], acc[i][f], 0, 0, 0);
            } else {
                // K=768 (24 kf): 4-slot register pipeline, prefetch distance 3
                const bf16_t* hin = hbuf[n & 1];
                const bf16_t* Ab[4];
#pragma unroll
                for (int i = 0; i < 4; ++i)
                    Ab[i] = hin + ((size_t)((mt * 16 + wave * 4 + i) * 24)) * 512 + lane * 8;
                const bf16_t* Bb[8];
#pragma unroll
                for (int f = 0; f < 8; ++f)
                    Bb[f] = Bs + ((size_t)(((nt * 2 + (f >> 2)) * 24) * 4 + (f & 3))) * 512 + lane * 8;

                s16x8 afr[4][4], bfr[4][8];
#pragma unroll
                for (int p = 0; p < 3; ++p) {
#pragma unroll
                    for (int i = 0; i < 4; ++i) afr[p][i] = *(const s16x8*)(Ab[i] + p * 512);
#pragma unroll
                    for (int f = 0; f < 8; ++f) bfr[p][f] = *(const s16x8*)(Bb[f] + (size_t)p * 2048);
                }
#pragma unroll
                for (int kt = 0; kt < 24; ++kt) {
                    if (kt + 3 < 24) {
                        const int pf = kt + 3, sl = pf & 3;
#pragma unroll
                        for (int i = 0; i < 4; ++i) afr[sl][i] = *(const s16x8*)(Ab[i] + pf * 512);
#pragma unroll
                        for (int f = 0; f < 8; ++f) bfr[sl][f] = *(const s16x8*)(Bb[f] + (size_t)pf * 2048);
                    }
                    const int s = kt & 3;
#pragma unroll
                    for (int i = 0; i < 4; ++i)
#pragma unroll
                        for (int f = 0; f < 8; ++f)
                            acc[i][f] = __builtin_amdgcn_mfma_f32_16x16x32_bf16(afr[s][i], bfr[s][f], acc[i][f], 0, 0, 0);
                }
            }

            // ---- epilogue ----
            if (!is_pred) {
                const float* bia = (n == 0) ? bi0 : biE;
                bf16_t* hout = hbuf[(n + 1) & 1];
#pragma unroll
                for (int i = 0; i < 4; ++i) {
                    const int mf = mt * 16 + wave * 4 + i;
                    bf16_t* hb = hout + ((size_t)(mf * 24 + nt)) * 512;
#pragma unroll
                    for (int r = 0; r < 4; ++r) {
#pragma unroll
                        for (int jg = 0; jg < 2; ++jg) {
                            float gi = acc[i][jg * 4 + 0][r] + bia[jg * 4 + 0];
                            float gf = acc[i][jg * 4 + 1][r] + bia[jg * 4 + 1];
                            float gg = acc[i][jg * 4 + 2][r] + bia[jg * 4 + 2];
                            float go = acc[i][jg * 4 + 3][r] + bia[jg * 4 + 3];
                            float si = sigf(gi);
                            float sf = sigf(gf);
                            float tg = tanh_fast(gg);
                            float so = sigf(go);
                            float cn = sf * cr[i][r][jg] + si * tg;
                            cr[i][r][jg] = cn;
                            int lp = (l4 * 4 + r) | ((jg * 2 + (l15 >> 3)) << 4);
                            hb[lp * 8 + (l15 & 7)] = (bf16_t)(so * tanh_fast(cn));
                        }
                    }
                }
            } else {
                const int t = n - 1;
#pragma unroll
                for (int f = 0; f < 8; ++f) {
                    int col = f * 16 + l15;
                    if (col < NPRED) {
#pragma unroll
                        for (int i = 0; i < 4; ++i)
#pragma unroll
                            for (int r = 0; r < 4; ++r) {
                                int row = mt * 256 + wave * 64 + i * 16 + l4 * 4 + r;
                                out[((size_t)row * 64 + t) * NPRED + col] = acc[i][f][r] + biE[f];
                            }
                    }
                }
            }
        }

        // ---- inter-step barrier (not after the last step) ----
        if (n < 64) {
            __syncthreads();                 // all waves' stores drained (vmcnt0 at barrier)
            if (tid == 0) {
                __threadfence();             // release: wbl2 -> h dirty lines to L3
                atomicAdd(bar, 1u);
                const unsigned int tgt = 256u * (unsigned int)(n + 1);
                while (__hip_atomic_load(bar, __ATOMIC_RELAXED, __HIP_MEMORY_SCOPE_AGENT) < tgt)
                    __builtin_amdgcn_s_sleep(2);
                __threadfence();             // acquire: inv stale L1/L2
            }
            __syncthreads();
        }
    }
}

// ---------------- fallback per-step kernel (verified R5 path) ---------------
__global__ __launch_bounds__(256, 2)
void step_kernel(const bf16_t* __restrict__ A,
                 const bf16_t* __restrict__ B,
                 const float* __restrict__ bias_r,
                 const float* __restrict__ b_d,
                 float* __restrict__ c_state,
                 bf16_t* __restrict__ h_out,
                 float* __restrict__ out,
                 int Knk, int nt_off, int t, int is_first)
{
    const int tid = threadIdx.x;
    const int wave = tid >> 6;
    const int lane = tid & 63;
    const int wr = wave >> 1, wc = wave & 1;
    const int l15 = lane & 15, l4 = lane >> 4;

    const int per = gridDim.x >> 3;
    const int g = (blockIdx.x & 7) * per + (blockIdx.x >> 3);
    const int nt = nt_off + (g >> 4);
    const int mt = g & 15;
    const int n0 = nt * 128;
    const bool is_pred = (nt >= 24);

    const bf16_t* Ab[4];
#pragma unroll
    for (int i = 0; i < 4; ++i)
        Ab[i] = A + ((size_t)((mt * 8 + wr * 4 + i) * Knk) * 64 + lane) * 8;
    const bf16_t* Bb[4];
#pragma unroll
    for (int f = 0; f < 4; ++f)
        Bb[f] = B + ((size_t)((nt * 2 + wc) * Knk * 4 + f) * 64 + lane) * 8;

    const int u = nt * 32 + wc * 16 + l15;
    const int slot = nt * 16 + mt;
    float* cbase = c_state + (((size_t)slot * 4 + wave) * 64 + lane) * 16;
    f32x4 cold4[4];
    float bi[4];
#pragma unroll
    for (int q = 0; q < 4; ++q) cold4[q] = f32x4{0.f, 0.f, 0.f, 0.f};
    if (!is_pred) {
        if (!is_first) {
#pragma unroll
            for (int q = 0; q < 4; ++q) cold4[q] = *(const f32x4*)(cbase + q * 4);
        }
#pragma unroll
        for (int f = 0; f < 4; ++f) bi[f] = bias_r[n0 + wc * 64 + f * 16 + l15];
    } else {
#pragma unroll
        for (int f = 0; f < 4; ++f) {
            int j = wc * 64 + f * 16 + l15;
            bi[f] = (j < NPRED) ? b_d[j] : 0.f;
        }
    }

    f32x4 acc[4][4];
#pragma unroll
    for (int i = 0; i < 4; ++i)
#pragma unroll
        for (int j = 0; j < 4; ++j) acc[i][j] = f32x4{0.f, 0.f, 0.f, 0.f};

    s16x8 afr[3][4], bfr[3][4];
    const int nk = Knk;
#define LOADK(BUF, KT) do {                                                          \
        _Pragma("unroll")                                                            \
        for (int _i = 0; _i < 4; ++_i)                                               \
            afr[BUF][_i] = *(const s16x8*)(Ab[_i] + (size_t)(KT) * 512);             \
        _Pragma("unroll")                                                            \
        for (int _f = 0; _f < 4; ++_f)                                               \
            bfr[BUF][_f] = *(const s16x8*)(Bb[_f] + (size_t)(KT) * 2048);            \
    } while (0)
#define MF(BUF) do {                                                                 \
        _Pragma("unroll")                                                            \
        for (int _i = 0; _i < 4; ++_i)                                               \
            _Pragma("unroll")                                                        \
            for (int _j = 0; _j < 4; ++_j)                                           \
                acc[_i][_j] = __builtin_amdgcn_mfma_f32_16x16x32_bf16(               \
                    afr[BUF][_i], bfr[BUF][_j], acc[_i][_j], 0, 0, 0);               \
    } while (0)
    LOADK(0, 0);
    LOADK(1, 1);
    const int nk3 = nk / 3;
    for (int b3 = 0; b3 < nk3; ++b3) {
        const int kt = b3 * 3;
        if (kt + 2 < nk) LOADK(2, kt + 2);
        MF(0);
        if (kt + 3 < nk) LOADK(0, kt + 3);
        MF(1);
        if (kt + 4 < nk) LOADK(1, kt + 4);
        MF(2);
    }
#undef LOADK
#undef MF

    if (!is_pred) {
        const int kq = wc * 2 + (l15 >> 3);
        const int jj = l15 & 7;
        f32x4 cnew4[4];
#pragma unroll
        for (int i = 0; i < 4; ++i) {
            const int mf = mt * 8 + wr * 4 + i;
            bf16_t* hb = h_out + (size_t)(mf * 24 + nt) * 512;
#pragma unroll
            for (int r = 0; r < 4; ++r) {
                float gi = acc[i][0][r] + bi[0];
                float gf = acc[i][1][r] + bi[1];
                float gg = acc[i][2][r] + bi[2];
                float go = acc[i][3][r] + bi[3];
                float si = sigf(gi);
                float sf = sigf(gf);
                float tg = tanh_fast(gg);
                float so = sigf(go);
                float cn = sf * cold4[i][r] + si * tg;
                cnew4[i][r] = cn;
                int lp = (l4 * 4 + r) | (kq << 4);
                hb[lp * 8 + jj] = (bf16_t)(so * tanh_fast(cn));
            }
        }
#pragma unroll
        for (int q = 0; q < 4; ++q) *(f32x4*)(cbase + q * 4) = cnew4[q];
    } else {
#pragma unroll
        for (int f = 0; f < 4; ++f) {
            int j = wc * 64 + f * 16 + l15;
            if (j < NPRED) {
#pragma unroll
                for (int i = 0; i < 4; ++i)
#pragma unroll
                    for (int r = 0; r < 4; ++r) {
                        int row = mt * 128 + wr * 64 + i * 16 + l4 * 4 + r;
                        out[((size_t)row * 64 + (t - 1)) * NPRED + j] = acc[i][f][r] + bi[f];
                    }
            }
        }
    }
}

extern "C" void kernel_launch(void* const* d_in, const int* in_sizes, int n_in,
                              void* d_out, int out_size, void* d_ws, size_t ws_size,
                              hipStream_t stream)
{
    const float* inputs = (const float*)d_in[0];
    const float* W_ih   = (const float*)d_in[1];
    const float* W_hh   = (const float*)d_in[2];
    const float* b_ih   = (const float*)d_in[3];
    const float* b_hh   = (const float*)d_in[4];
    const float* W_d    = (const float*)d_in[5];
    const float* b_d    = (const float*)d_in[6];
    float* out = (float*)d_out;

    char* ws = (char*)d_ws;
    size_t off = 0;
    auto alloc = [&](size_t bytes) -> char* {
        char* p = ws + off;
        off = (off + bytes + 255) & ~(size_t)255;
        return p;
    };
    bf16_t* B0T   = (bf16_t*)alloc((size_t)NCOLS * 96 * 2);
    bf16_t* B0s   = (bf16_t*)alloc((size_t)NCOLS * 96 * 2);
    bf16_t* BeffT = (bf16_t*)alloc((size_t)3200 * UNITS * 2);
    bf16_t* Bs    = (bf16_t*)alloc((size_t)3200 * UNITS * 2);
    bf16_t* x0s   = (bf16_t*)alloc((size_t)MROWS * 96 * 2);
    bf16_t* h0    = (bf16_t*)alloc((size_t)MROWS * UNITS * 2);
    bf16_t* h1    = (bf16_t*)alloc((size_t)MROWS * UNITS * 2);
    float*  cst   = (float*)alloc((size_t)400 * 4 * 64 * 16 * 4);
    float*  b0r   = (float*)alloc(NCOLS * 4);
    float*  beffr = (float*)alloc(NCOLS * 4);
    unsigned int* ctrs = (unsigned int*)alloc(64 * 4);

    prep_zero <<<1, 64, 0, stream>>>(ctrs);
    prep_b0   <<<(NCOLS * 96 + 255) / 256, 256, 0, stream>>>(W_ih, B0T);
    prep_swz  <<<(NCOLS * 96 + 255) / 256, 256, 0, stream>>>(B0T, B0s, 3, 96, NCOLS * 96);
    prep_x0   <<<(MROWS * 96) / 256, 256, 0, stream>>>(inputs, x0s);
    prep_bias <<<(NCOLS + 255) / 256, 256, 0, stream>>>(b_ih, b_hh, W_ih, b_d, b0r, beffr);
    prep_beff2<<<dim3(48, 12), 256, 0, stream>>>(W_hh, W_ih, W_d, BeffT);
    prep_wdt  <<<(128 * UNITS) / 256, 256, 0, stream>>>(W_d, BeffT);
    prep_swz  <<<(3200 * UNITS + 255) / 256, 256, 0, stream>>>(BeffT, Bs, 24, UNITS, 3200 * UNITS);

    void* a0 = (void*)x0s; void* a1 = (void*)B0s; void* a2 = (void*)Bs;
    void* a3 = (void*)b0r; void* a4 = (void*)beffr; void* a5 = (void*)b_d;
    void* a6 = (void*)h0;  void* a7 = (void*)h1;  void* a8 = (void*)out;
    void* a9 = (void*)ctrs;
    void* args[] = { &a0, &a1, &a2, &a3, &a4, &a5, &a6, &a7, &a8, &a9 };

    hipError_t err = hipLaunchCooperativeKernel((const void*)persist_kernel,
                                                dim3(256), dim3(256), args, 0, stream);
    if (err != hipSuccess) {
        (void)hipGetLastError();
        // fallback: verified R5 per-step path
        bf16_t* h[2] = {h0, h1};
        step_kernel<<<384, 256, 0, stream>>>(x0s, B0s, b0r, b_d, cst, h[1], out, 3, 0, 0, 1);
        for (int n = 1; n < 64; ++n)
            step_kernel<<<400, 256, 0, stream>>>(h[n & 1], Bs, beffr, b_d, cst,
                                                 h[(n + 1) & 1], out, 24, 0, n, 0);
        step_kernel<<<16, 256, 0, stream>>>(h[0], Bs, beffr, b_d, cst, h[1], out,
                                            24, 24, 64, 0);
    }
    (void)cst; (void)ws_size; (void)in_sizes; (void)n_in; (void)out_size;
}

// Round 8
// 3882.898 us; speedup vs baseline: 1.2952x; 1.2952x over previous
//
#include <hip/hip_runtime.h>
#include <hip/hip_bf16.h>
#include <stdint.h>

typedef __hip_bfloat16 bf16_t;
typedef __attribute__((ext_vector_type(4))) float f32x4;
typedef __attribute__((ext_vector_type(8))) short s16x8;

#define UNITS 768
#define NCOLS 3072        // 4*UNITS (gates, reordered)
#define NPRED 96
#define MROWS 2048

__device__ __forceinline__ float sigf(float x) {
    return __builtin_amdgcn_rcpf(1.f + __expf(-x));
}
__device__ __forceinline__ float tanh_fast(float x) {
    return 1.f - 2.f * __builtin_amdgcn_rcpf(1.f + __expf(2.f * x));
}

// ---------------- prep kernels (once per launch) ---------------

__global__ void prep_zero(unsigned int* c) {
    int i = blockIdx.x * 256 + threadIdx.x;
    if (i < 1024) c[i] = 0u;
}

// B0T[c][k] = W_ih[g*768+u][k], c-reordered (linear), K=96
__global__ void prep_b0(const float* __restrict__ W_ih, bf16_t* __restrict__ B0T) {
    int idx = blockIdx.x * 256 + threadIdx.x;
    if (idx >= NCOLS * 96) return;
    int c = idx / 96, k = idx % 96;
    int u = ((c >> 6) << 4) + (c & 15);
    int g = (c >> 4) & 3;
    B0T[idx] = (bf16_t)W_ih[(g * UNITS + u) * 96 + k];
}

// x0 in A-fragment layout
__global__ void prep_x0(const float* __restrict__ inputs, bf16_t* __restrict__ x0) {
    int idx = blockIdx.x * 256 + threadIdx.x; // 2048*96 exactly
    int j = idx & 7;
    int l = (idx >> 3) & 63;
    int fg = idx >> 9;          // mf*3 + kf
    int kf = fg % 3;
    int mf = fg / 3;
    int m = mf * 16 + (l & 15);
    int k = kf * 32 + (l >> 4) * 8 + j;
    x0[idx] = (bf16_t)inputs[(m * 24 + 23) * 96 + k];
}

__global__ void prep_bias(const float* __restrict__ b_ih, const float* __restrict__ b_hh,
                          const float* __restrict__ W_ih, const float* __restrict__ b_d,
                          float* __restrict__ b0_r, float* __restrict__ beff_r) {
    int c = blockIdx.x * 256 + threadIdx.x;
    if (c >= NCOLS) return;
    int u = ((c >> 6) << 4) + (c & 15);
    int g = (c >> 4) & 3;
    int r = g * UNITS + u;
    float v = b_ih[r] + b_hh[r];
    float acc = 0.f;
    for (int j = 0; j < 96; ++j) acc += W_ih[r * 96 + j] * b_d[j];
    b0_r[c] = v;
    beff_r[c] = v + acc;
}

// BeffT[c][k] = W_hh[r(c)][k] + sum_j W_ih[r(c)][j]*W_d[j][k]
__global__ void prep_beff2(const float* __restrict__ W_hh, const float* __restrict__ W_ih,
                           const float* __restrict__ W_d, bf16_t* __restrict__ BeffT) {
    __shared__ float sWih[64][96];
    __shared__ float sWd[96][64];
    const int c0 = blockIdx.x * 64, k0 = blockIdx.y * 64;
    const int tid = threadIdx.x;
    for (int i = tid; i < 64 * 96; i += 256) {
        int cc = i / 96, j = i % 96;
        int c = c0 + cc;
        int u = ((c >> 6) << 4) + (c & 15);
        int g = (c >> 4) & 3;
        sWih[cc][j] = W_ih[(g * UNITS + u) * 96 + j];
    }
    for (int i = tid; i < 96 * 64; i += 256) {
        int j = i / 64, kk = i % 64;
        sWd[j][kk] = W_d[j * UNITS + k0 + kk];
    }
    __syncthreads();
    const int kk = tid & 63;
    const int cc0 = (tid >> 6) * 16;
    for (int cc = cc0; cc < cc0 + 16; ++cc) {
        float acc = 0.f;
#pragma unroll 12
        for (int j = 0; j < 96; ++j) acc += sWih[cc][j] * sWd[j][kk];
        int c = c0 + cc;
        int u = ((c >> 6) << 4) + (c & 15);
        int g = (c >> 4) & 3;
        int r = g * UNITS + u;
        BeffT[(size_t)c * UNITS + k0 + kk] = (bf16_t)(W_hh[(size_t)r * UNITS + k0 + kk] + acc);
    }
}

__global__ void prep_wdt(const float* __restrict__ W_d, bf16_t* __restrict__ BeffT) {
    int idx = blockIdx.x * 256 + threadIdx.x; // 128*768
    int c = idx / UNITS, k = idx % UNITS;
    float v = (c < NPRED) ? W_d[c * UNITS + k] : 0.f;
    BeffT[(size_t)(NCOLS + c) * UNITS + k] = (bf16_t)v;
}

// swizzle linear [c][K] -> B-fragment order
__global__ void prep_swz(const bf16_t* __restrict__ src, bf16_t* __restrict__ dst,
                         int Knk, int K, int total) {
    int idx = blockIdx.x * 256 + threadIdx.x;
    if (idx >= total) return;
    int j = idx & 7;
    int l = (idx >> 3) & 63;
    int fg = idx >> 9;
    int f = fg & 3;
    int rest = fg >> 2;
    int kf = rest % Knk;
    int nw = rest / Knk;
    int c = (nw >> 1) * 128 + (nw & 1) * 64 + f * 16 + (l & 15);
    int k = kf * 32 + (l >> 4) * 8 + j;
    dst[idx] = src[(size_t)c * K + k];
}

// ---------------- persistent kernel: XCD-self-contained, fence-free sync ---------------
// 256 blocks x 256 threads (1/CU). Fast mode (verified placement): XCD x owns
// M-rows [x*256, x*256+256); its 25 blocks are nt=0..24 (nt 24 = pred). h for those
// rows never leaves XCD x's L2 -> inter-step sync is a per-XCD counter with NO
// threadfence; weights stay L2-resident all 64 steps. L1 staleness handled by a
// per-CU buffer_inv (L1-only). If registration can't verify >=25 blocks per XCD,
// fall back to the R6 globally-fenced barrier (slow but placement-independent).
__global__ __launch_bounds__(256, 1)
void persist_kernel(const bf16_t* __restrict__ x0s,
                    const bf16_t* __restrict__ B0s,
                    const bf16_t* __restrict__ Bs,
                    const float* __restrict__ b0r,
                    const float* __restrict__ beffr,
                    const float* __restrict__ b_d,
                    bf16_t* __restrict__ h0,
                    bf16_t* __restrict__ h1,
                    float* __restrict__ out,
                    unsigned int* __restrict__ ctrs)
{
    const int tid = threadIdx.x;
    const int wave = tid >> 6;
    const int lane = tid & 63;
    const int l15 = lane & 15, l4 = lane >> 4;

    __shared__ int s_id, s_mode, s_cnt, s_x;

    // ---- registration: claim XCD, verify coverage, pick mode ----
    if (tid == 0) {
        unsigned int x;
        asm volatile("s_getreg_b32 %0, hwreg(20, 0, 32)" : "=s"(x));  // HW_REG_XCC_ID
        x &= 7u;
        unsigned int r = atomicAdd(&ctrs[x], 1u);
        __threadfence();                               // order r-add before g-add
        unsigned int gq = atomicAdd(&ctrs[8], 1u);
        while (__hip_atomic_load(&ctrs[8], __ATOMIC_RELAXED, __HIP_MEMORY_SCOPE_AGENT) < 256u)
            __builtin_amdgcn_s_sleep(2);
        __threadfence();
        unsigned int mn = 0xffffffffu;
        for (int y = 0; y < 8; ++y) {
            unsigned int v = __hip_atomic_load(&ctrs[y], __ATOMIC_RELAXED, __HIP_MEMORY_SCOPE_AGENT);
            mn = (v < mn) ? v : mn;
        }
        unsigned int cx = __hip_atomic_load(&ctrs[x], __ATOMIC_RELAXED, __HIP_MEMORY_SCOPE_AGENT);
        int mode = (mn >= 25u) ? 0 : 1;
        int id;
        if (mode == 0) id = (r < 25u) ? (int)r : -1;          // nt = r, mt = x
        else           id = (gq < 200u) ? (int)gq : -1;       // mt = id&7, nt = id>>3
        s_id = id; s_mode = mode; s_cnt = (int)cx; s_x = (int)x;
    }
    __syncthreads();
    const int id = s_id;
    const int mode = s_mode;
    const int xcd = s_x;
    const unsigned int xcnt = (unsigned int)s_cnt;
    const bool active = (id >= 0);
    const int mt = active ? (mode == 0 ? xcd : (id & 7)) : 0;
    const int nt = active ? (mode == 0 ? id : (id >> 3)) : 0;
    const bool is_pred = active && (nt == 24);

    unsigned int* gbar = &ctrs[9];
    unsigned int* xbar = &ctrs[32 + 32 * xcd];   // separate cache line per XCD
    bf16_t* hbuf[2] = {h0, h1};

    // ---- per-lane constants ----
    float bi0[8], biE[8];
    if (active) {
        if (!is_pred) {
#pragma unroll
            for (int f = 0; f < 8; ++f) {
                bi0[f] = b0r[nt * 128 + f * 16 + l15];
                biE[f] = beffr[nt * 128 + f * 16 + l15];
            }
        } else {
#pragma unroll
            for (int f = 0; f < 8; ++f) {
                int col = f * 16 + l15;
                biE[f] = (col < NPRED) ? b_d[col] : 0.f;
                bi0[f] = biE[f];
            }
        }
    }

    // c-state in registers
    float cr[4][4][2];
#pragma unroll
    for (int i = 0; i < 4; ++i)
#pragma unroll
        for (int r = 0; r < 4; ++r) { cr[i][r][0] = 0.f; cr[i][r][1] = 0.f; }

    for (int n = 0; n <= 64; ++n) {
        const bool doit = active && (n == 0 ? !is_pred : (n == 64 ? is_pred : true));
        if (doit) {
            f32x4 acc[4][8];
#pragma unroll
            for (int i = 0; i < 4; ++i)
#pragma unroll
                for (int f = 0; f < 8; ++f) acc[i][f] = f32x4{0.f, 0.f, 0.f, 0.f};

            if (n == 0) {
                s16x8 a3[3][4], b3[3][8];
#pragma unroll
                for (int p = 0; p < 3; ++p) {
#pragma unroll
                    for (int i = 0; i < 4; ++i)
                        a3[p][i] = *(const s16x8*)(x0s + ((size_t)((mt * 16 + wave * 4 + i) * 3 + p)) * 512 + lane * 8);
#pragma unroll
                    for (int f = 0; f < 8; ++f)
                        b3[p][f] = *(const s16x8*)(B0s + ((size_t)(((nt * 2 + (f >> 2)) * 3 + p) * 4 + (f & 3))) * 512 + lane * 8);
                }
#pragma unroll
                for (int p = 0; p < 3; ++p)
#pragma unroll
                    for (int i = 0; i < 4; ++i)
#pragma unroll
                        for (int f = 0; f < 8; ++f)
                            acc[i][f] = __builtin_amdgcn_mfma_f32_16x16x32_bf16(a3[p][i], b3[p][f], acc[i][f], 0, 0, 0);
            } else {
                const bf16_t* hin = hbuf[n & 1];
                const bf16_t* Ab[4];
#pragma unroll
                for (int i = 0; i < 4; ++i)
                    Ab[i] = hin + ((size_t)((mt * 16 + wave * 4 + i) * 24)) * 512 + lane * 8;
                const bf16_t* Bb[8];
#pragma unroll
                for (int f = 0; f < 8; ++f)
                    Bb[f] = Bs + ((size_t)(((nt * 2 + (f >> 2)) * 24) * 4 + (f & 3))) * 512 + lane * 8;

                s16x8 afr[4][4], bfr[4][8];
#pragma unroll
                for (int p = 0; p < 3; ++p) {
#pragma unroll
                    for (int i = 0; i < 4; ++i) afr[p][i] = *(const s16x8*)(Ab[i] + p * 512);
#pragma unroll
                    for (int f = 0; f < 8; ++f) bfr[p][f] = *(const s16x8*)(Bb[f] + (size_t)p * 2048);
                }
#pragma unroll
                for (int kt = 0; kt < 24; ++kt) {
                    if (kt + 3 < 24) {
                        const int pf = kt + 3, sl = pf & 3;
#pragma unroll
                        for (int i = 0; i < 4; ++i) afr[sl][i] = *(const s16x8*)(Ab[i] + pf * 512);
#pragma unroll
                        for (int f = 0; f < 8; ++f) bfr[sl][f] = *(const s16x8*)(Bb[f] + (size_t)pf * 2048);
                    }
                    const int s = kt & 3;
#pragma unroll
                    for (int i = 0; i < 4; ++i)
#pragma unroll
                        for (int f = 0; f < 8; ++f)
                            acc[i][f] = __builtin_amdgcn_mfma_f32_16x16x32_bf16(afr[s][i], bfr[s][f], acc[i][f], 0, 0, 0);
                }
            }

            // ---- epilogue ----
            if (!is_pred) {
                const float* bia = (n == 0) ? bi0 : biE;
                bf16_t* hout = hbuf[(n + 1) & 1];
#pragma unroll
                for (int i = 0; i < 4; ++i) {
                    const int mf = mt * 16 + wave * 4 + i;
                    bf16_t* hb = hout + ((size_t)(mf * 24 + nt)) * 512;
#pragma unroll
                    for (int r = 0; r < 4; ++r) {
#pragma unroll
                        for (int jg = 0; jg < 2; ++jg) {
                            float gi = acc[i][jg * 4 + 0][r] + bia[jg * 4 + 0];
                            float gf = acc[i][jg * 4 + 1][r] + bia[jg * 4 + 1];
                            float gg = acc[i][jg * 4 + 2][r] + bia[jg * 4 + 2];
                            float go = acc[i][jg * 4 + 3][r] + bia[jg * 4 + 3];
                            float si = sigf(gi);
                            float sf = sigf(gf);
                            float tg = tanh_fast(gg);
                            float so = sigf(go);
                            float cn = sf * cr[i][r][jg] + si * tg;
                            cr[i][r][jg] = cn;
                            int lp = (l4 * 4 + r) | ((jg * 2 + (l15 >> 3)) << 4);
                            hb[lp * 8 + (l15 & 7)] = (bf16_t)(so * tanh_fast(cn));
                        }
                    }
                }
            } else {
                const int t = n - 1;
#pragma unroll
                for (int f = 0; f < 8; ++f) {
                    int col = f * 16 + l15;
                    if (col < NPRED) {
#pragma unroll
                        for (int i = 0; i < 4; ++i)
#pragma unroll
                            for (int r = 0; r < 4; ++r) {
                                int row = mt * 256 + wave * 64 + i * 16 + l4 * 4 + r;
                                out[((size_t)row * 64 + t) * NPRED + col] = acc[i][f][r] + biE[f];
                            }
                    }
                }
            }
        }

        // ---- inter-step barrier ----
        if (n < 64) {
            __syncthreads();                 // block's h stores drained (vmcnt 0)
            if (mode == 0) {
                // fence-free per-XCD barrier: h stays in this XCD's L2
                if (tid == 0) {
                    atomicAdd(xbar, 1u);
                    const unsigned int tgt = xcnt * (unsigned int)(n + 1);
                    while (__hip_atomic_load(xbar, __ATOMIC_RELAXED, __HIP_MEMORY_SCOPE_AGENT) < tgt)
                        __builtin_amdgcn_s_sleep(2);
                }
                if (wave == 0) {
                    // invalidate this CU's vector L1 only; L2 untouched
                    asm volatile("buffer_inv\n\ts_waitcnt vmcnt(0)" ::: "memory");
                }
                __syncthreads();
            } else {
                if (tid == 0) {
                    __threadfence();
                    atomicAdd(gbar, 1u);
                    const unsigned int tgt = 256u * (unsigned int)(n + 1);
                    while (__hip_atomic_load(gbar, __ATOMIC_RELAXED, __HIP_MEMORY_SCOPE_AGENT) < tgt)
                        __builtin_amdgcn_s_sleep(2);
                    __threadfence();
                }
                __syncthreads();
            }
        }
    }
}

// ---------------- fallback per-step kernel (verified R5 path) ---------------
__global__ __launch_bounds__(256, 2)
void step_kernel(const bf16_t* __restrict__ A,
                 const bf16_t* __restrict__ B,
                 const float* __restrict__ bias_r,
                 const float* __restrict__ b_d,
                 float* __restrict__ c_state,
                 bf16_t* __restrict__ h_out,
                 float* __restrict__ out,
                 int Knk, int nt_off, int t, int is_first)
{
    const int tid = threadIdx.x;
    const int wave = tid >> 6;
    const int lane = tid & 63;
    const int wr = wave >> 1, wc = wave & 1;
    const int l15 = lane & 15, l4 = lane >> 4;

    const int per = gridDim.x >> 3;
    const int g = (blockIdx.x & 7) * per + (blockIdx.x >> 3);
    const int nt = nt_off + (g >> 4);
    const int mt = g & 15;
    const int n0 = nt * 128;
    const bool is_pred = (nt >= 24);

    const bf16_t* Ab[4];
#pragma unroll
    for (int i = 0; i < 4; ++i)
        Ab[i] = A + ((size_t)((mt * 8 + wr * 4 + i) * Knk) * 64 + lane) * 8;
    const bf16_t* Bb[4];
#pragma unroll
    for (int f = 0; f < 4; ++f)
        Bb[f] = B + ((size_t)((nt * 2 + wc) * Knk * 4 + f) * 64 + lane) * 8;

    const int u = nt * 32 + wc * 16 + l15;
    const int slot = nt * 16 + mt;
    float* cbase = c_state + (((size_t)slot * 4 + wave) * 64 + lane) * 16;
    f32x4 cold4[4];
    float bi[4];
#pragma unroll
    for (int q = 0; q < 4; ++q) cold4[q] = f32x4{0.f, 0.f, 0.f, 0.f};
    if (!is_pred) {
        if (!is_first) {
#pragma unroll
            for (int q = 0; q < 4; ++q) cold4[q] = *(const f32x4*)(cbase + q * 4);
        }
#pragma unroll
        for (int f = 0; f < 4; ++f) bi[f] = bias_r[n0 + wc * 64 + f * 16 + l15];
    } else {
#pragma unroll
        for (int f = 0; f < 4; ++f) {
            int j = wc * 64 + f * 16 + l15;
            bi[f] = (j < NPRED) ? b_d[j] : 0.f;
        }
    }

    f32x4 acc[4][4];
#pragma unroll
    for (int i = 0; i < 4; ++i)
#pragma unroll
        for (int j = 0; j < 4; ++j) acc[i][j] = f32x4{0.f, 0.f, 0.f, 0.f};

    s16x8 afr[3][4], bfr[3][4];
    const int nk = Knk;
#define LOADK(BUF, KT) do {                                                          \
        _Pragma("unroll")                                                            \
        for (int _i = 0; _i < 4; ++_i)                                               \
            afr[BUF][_i] = *(const s16x8*)(Ab[_i] + (size_t)(KT) * 512);             \
        _Pragma("unroll")                                                            \
        for (int _f = 0; _f < 4; ++_f)                                               \
            bfr[BUF][_f] = *(const s16x8*)(Bb[_f] + (size_t)(KT) * 2048);            \
    } while (0)
#define MF(BUF) do {                                                                 \
        _Pragma("unroll")                                                            \
        for (int _i = 0; _i < 4; ++_i)                                               \
            _Pragma("unroll")                                                        \
            for (int _j = 0; _j < 4; ++_j)                                           \
                acc[_i][_j] = __builtin_amdgcn_mfma_f32_16x16x32_bf16(               \
                    afr[BUF][_i], bfr[BUF][_j], acc[_i][_j], 0, 0, 0);               \
    } while (0)
    LOADK(0, 0);
    LOADK(1, 1);
    const int nk3 = nk / 3;
    for (int b3 = 0; b3 < nk3; ++b3) {
        const int kt = b3 * 3;
        if (kt + 2 < nk) LOADK(2, kt + 2);
        MF(0);
        if (kt + 3 < nk) LOADK(0, kt + 3);
        MF(1);
        if (kt + 4 < nk) LOADK(1, kt + 4);
        MF(2);
    }
#undef LOADK
#undef MF

    if (!is_pred) {
        const int kq = wc * 2 + (l15 >> 3);
        const int jj = l15 & 7;
        f32x4 cnew4[4];
#pragma unroll
        for (int i = 0; i < 4; ++i) {
            const int mf = mt * 8 + wr * 4 + i;
            bf16_t* hb = h_out + (size_t)(mf * 24 + nt) * 512;
#pragma unroll
            for (int r = 0; r < 4; ++r) {
                float gi = acc[i][0][r] + bi[0];
                float gf = acc[i][1][r] + bi[1];
                float gg = acc[i][2][r] + bi[2];
                float go = acc[i][3][r] + bi[3];
                float si = sigf(gi);
                float sf = sigf(gf);
                float tg = tanh_fast(gg);
                float so = sigf(go);
                float cn = sf * cold4[i][r] + si * tg;
                cnew4[i][r] = cn;
                int lp = (l4 * 4 + r) | (kq << 4);
                hb[lp * 8 + jj] = (bf16_t)(so * tanh_fast(cn));
            }
        }
#pragma unroll
        for (int q = 0; q < 4; ++q) *(f32x4*)(cbase + q * 4) = cnew4[q];
    } else {
#pragma unroll
        for (int f = 0; f < 4; ++f) {
            int j = wc * 64 + f * 16 + l15;
            if (j < NPRED) {
#pragma unroll
                for (int i = 0; i < 4; ++i)
#pragma unroll
                    for (int r = 0; r < 4; ++r) {
                        int row = mt * 128 + wr * 64 + i * 16 + l4 * 4 + r;
                        out[((size_t)row * 64 + (t - 1)) * NPRED + j] = acc[i][f][r] + bi[f];
                    }
            }
        }
    }
}

extern "C" void kernel_launch(void* const* d_in, const int* in_sizes, int n_in,
                              void* d_out, int out_size, void* d_ws, size_t ws_size,
                              hipStream_t stream)
{
    const float* inputs = (const float*)d_in[0];
    const float* W_ih   = (const float*)d_in[1];
    const float* W_hh   = (const float*)d_in[2];
    const float* b_ih   = (const float*)d_in[3];
    const float* b_hh   = (const float*)d_in[4];
    const float* W_d    = (const float*)d_in[5];
    const float* b_d    = (const float*)d_in[6];
    float* out = (float*)d_out;

    char* ws = (char*)d_ws;
    size_t off = 0;
    auto alloc = [&](size_t bytes) -> char* {
        char* p = ws + off;
        off = (off + bytes + 255) & ~(size_t)255;
        return p;
    };
    bf16_t* B0T   = (bf16_t*)alloc((size_t)NCOLS * 96 * 2);
    bf16_t* B0s   = (bf16_t*)alloc((size_t)NCOLS * 96 * 2);
    bf16_t* BeffT = (bf16_t*)alloc((size_t)3200 * UNITS * 2);
    bf16_t* Bs    = (bf16_t*)alloc((size_t)3200 * UNITS * 2);
    bf16_t* x0s   = (bf16_t*)alloc((size_t)MROWS * 96 * 2);
    bf16_t* h0    = (bf16_t*)alloc((size_t)MROWS * UNITS * 2);
    bf16_t* h1    = (bf16_t*)alloc((size_t)MROWS * UNITS * 2);
    float*  cst   = (float*)alloc((size_t)400 * 4 * 64 * 16 * 4);
    float*  b0r   = (float*)alloc(NCOLS * 4);
    float*  beffr = (float*)alloc(NCOLS * 4);
    unsigned int* ctrs = (unsigned int*)alloc(1024 * 4);

    prep_zero <<<4, 256, 0, stream>>>(ctrs);
    prep_b0   <<<(NCOLS * 96 + 255) / 256, 256, 0, stream>>>(W_ih, B0T);
    prep_swz  <<<(NCOLS * 96 + 255) / 256, 256, 0, stream>>>(B0T, B0s, 3, 96, NCOLS * 96);
    prep_x0   <<<(MROWS * 96) / 256, 256, 0, stream>>>(inputs, x0s);
    prep_bias <<<(NCOLS + 255) / 256, 256, 0, stream>>>(b_ih, b_hh, W_ih, b_d, b0r, beffr);
    prep_beff2<<<dim3(48, 12), 256, 0, stream>>>(W_hh, W_ih, W_d, BeffT);
    prep_wdt  <<<(128 * UNITS) / 256, 256, 0, stream>>>(W_d, BeffT);
    prep_swz  <<<(3200 * UNITS + 255) / 256, 256, 0, stream>>>(BeffT, Bs, 24, UNITS, 3200 * UNITS);

    void* a0 = (void*)x0s; void* a1 = (void*)B0s; void* a2 = (void*)Bs;
    void* a3 = (void*)b0r; void* a4 = (void*)beffr; void* a5 = (void*)b_d;
    void* a6 = (void*)h0;  void* a7 = (void*)h1;  void* a8 = (void*)out;
    void* a9 = (void*)ctrs;
    void* args[] = { &a0, &a1, &a2, &a3, &a4, &a5, &a6, &a7, &a8, &a9 };

    hipError_t err = hipLaunchCooperativeKernel((const void*)persist_kernel,
                                                dim3(256), dim3(256), args, 0, stream);
    if (err != hipSuccess) {
        (void)hipGetLastError();
        // fallback: verified R5 per-step path
        bf16_t* h[2] = {h0, h1};
        step_kernel<<<384, 256, 0, stream>>>(x0s, B0s, b0r, b_d, cst, h[1], out, 3, 0, 0, 1);
        for (int n = 1; n < 64; ++n)
            step_kernel<<<400, 256, 0, stream>>>(h[n & 1], Bs, beffr, b_d, cst,
                                                 h[(n + 1) & 1], out, 24, 0, n, 0);
        step_kernel<<<16, 256, 0, stream>>>(h[0], Bs, beffr, b_d, cst, h[1], out,
                                            24, 24, 64, 0);
    }
    (void)cst; (void)ws_size; (void)in_sizes; (void)n_in; (void)out_size;
}